// Round 16
// baseline (32.916 us; speedup 1.0000x reference)
//
#include <hip/hip_runtime.h>
#include <math.h>

#define N 6144
#define E 64
#define H 8
#define D 512
#define TD 1536  // 3*D
#define EPS 1e-5f
#define SCALE 0.04419417382415922f  // 1/sqrt(512)
#define RMAX 64   // max segment size; multinomial max ~41, P(>64) ~1e-14

typedef __attribute__((ext_vector_type(8))) short bf16x8;
typedef __attribute__((ext_vector_type(4))) float f32x4;

static __device__ __forceinline__ unsigned short f2bf(float f) {
    union { float f; unsigned int u; } v; v.f = f;
    unsigned int r = v.u + 0x7FFFu + ((v.u >> 16) & 1u);  // RNE
    return (unsigned short)(r >> 16);
}
static __device__ __forceinline__ float bf2f(unsigned short u) {
    union { unsigned int u; float f; } v; v.u = ((unsigned int)u) << 16;
    return v.f;
}

// ---------------------------------------------------------------------------
// Kernel 0: prep. Blocks [0,24): bound table. [24,72): Wt transpose (one
// thread per (j,k-octet): 8 coalesced f32 loads + one 16B store). [72,88):
// Wot same. [88,856): LN1, TWO rows per wave via 32-lane halves (shfl_xor
// offs 1..16 stay within the half) — halves the dispatch ramp vs R15.
// ---------------------------------------------------------------------------
__global__ __launch_bounds__(256) void prep_kernel(
    const float* __restrict__ x, const float* __restrict__ ln1g,
    const float* __restrict__ ln1b, const float* __restrict__ W_qkv,
    const float* __restrict__ W_out, const int* __restrict__ batch,
    unsigned short* __restrict__ Wt, unsigned short* __restrict__ Wot,
    int* __restrict__ bound, unsigned short* __restrict__ h1g)
{
    const int t = threadIdx.x, lane = t & 63, wv = t >> 6;
    const int bx = blockIdx.x;
    if (bx < 24) {                                     // bound table
        const int tid = bx * 256 + t;
        const int bv = batch[tid];
        const int prev = tid ? batch[tid - 1] : -1;
        if (bv != prev)
            for (int v = prev + 1; v <= bv; ++v) bound[v] = tid;
        if (tid == N - 1)
            for (int v = bv + 1; v <= 256; ++v) bound[v] = N;
    } else if (bx < 72) {                              // Wt[j][k] = W_qkv[k][j]
        const int w = (bx - 24) * 256 + t;             // [0, 12288)
        const int j = w % TD, ko = w / TD;             // ko in [0,8)
        bf16x8 o;
        #pragma unroll
        for (int i = 0; i < 8; ++i)                    // coalesced across j
            o[i] = (short)f2bf(W_qkv[(size_t)(ko * 8 + i) * TD + j]);
        *(bf16x8*)&Wt[(size_t)j * 64 + ko * 8] = o;    // one 16B store
    } else if (bx < 88) {                              // Wot[j][k] = W_out[k][j]
        const int w = (bx - 72) * 256 + t;             // [0, 4096)
        const int j = w & 63, ko = w >> 6;             // ko in [0,64)
        bf16x8 o;
        #pragma unroll
        for (int i = 0; i < 8; ++i)                    // coalesced across j
            o[i] = (short)f2bf(W_out[(size_t)(ko * 8 + i) * 64 + j]);
        *(bf16x8*)&Wot[(size_t)j * 512 + ko * 8] = o;  // one 16B store
    } else {                                           // LN1, 2 rows per wave
        const int half = lane >> 5;                    // row select in wave
        const int l32  = lane & 31;
        const int row = (bx - 88) * 8 + wv * 2 + half; // [0, 6144)
        const float v0 = x[(size_t)row * E + l32];
        const float v1 = x[(size_t)row * E + 32 + l32];
        float sm = v0 + v1, sq = v0 * v0 + v1 * v1;
        #pragma unroll
        for (int off = 1; off < 32; off <<= 1) {       // stays within 32-group
            sm += __shfl_xor(sm, off);
            sq += __shfl_xor(sq, off);
        }
        const float mean = sm * (1.f / 64.f);
        const float var  = sq * (1.f / 64.f) - mean * mean;
        const float rstd = rsqrtf(var + EPS);
        h1g[(size_t)row * 64 + l32] =
            f2bf((v0 - mean) * rstd * ln1g[l32] + ln1b[l32]);
        h1g[(size_t)row * 64 + 32 + l32] =
            f2bf((v1 - mean) * rstd * ln1g[32 + l32] + ln1b[32 + l32]);
    }
}

// ---------------------------------------------------------------------------
// Kernel 1: one block per (segment, head). QKV (wave per column-tile), then
// attention with two-level wave split (R14):
//   phase 1: wave per (qt, kt) 16x16 score tile -> Ps; __syncthreads;
//   phase 2: wave per (qt, 32-col half) PV; O bounced through dead Qs
//            (NOT Ps — other waves still read Ps) -> coalesced 16B stores.
// Fusion ruled out by measurement: grid-sync (R5), agent atomics (R12).
// Frag maps (verified R3-R15): A[row=lr][k=lg*8+j], B[col=lr][k=lg*8+j],
// D[col=lr][row=lg*4+r].
// ---------------------------------------------------------------------------
__global__ __launch_bounds__(256) void seghead_kernel(
    const unsigned short* __restrict__ h1g, const unsigned short* __restrict__ Wt,
    const float* __restrict__ b_qkv, const int* __restrict__ bound,
    unsigned short* __restrict__ attb)
{
    __shared__ unsigned short Qs[RMAX][72];     // per-head Q [q][d] / O bounce
    __shared__ unsigned short Ks[RMAX][72];     // per-head K [key][d]
    __shared__ unsigned short Vs[64][72];       // per-head V^T [d][key]
    __shared__ unsigned short Ps[RMAX][72];     // P [q][key]

    const int t = threadIdx.x, lane = t & 63, wv = t >> 6;
    const int lr = lane & 15, lg = lane >> 4;
    const int b = blockIdx.x, h = blockIdx.y;

    // bound loads first: longest scalar dependency chain (R -> NT/KB/loops)
    const int s = bound[b];
    const int e = bound[b + 1];

    // W fragments for this wave's column tile (overlap under bound latency)
    const int ct = wv;
    const int jK = h * 64 + ct * 16;
    const int jQ = 512 + jK;
    const int jV = 1024 + jK;
    const bf16x8 wK0 = *(const bf16x8*)&Wt[(size_t)(jK + lr) * 64 + lg * 8];
    const bf16x8 wK1 = *(const bf16x8*)&Wt[(size_t)(jK + lr) * 64 + 32 + lg * 8];
    const bf16x8 wQ0 = *(const bf16x8*)&Wt[(size_t)(jQ + lr) * 64 + lg * 8];
    const bf16x8 wQ1 = *(const bf16x8*)&Wt[(size_t)(jQ + lr) * 64 + 32 + lg * 8];
    const bf16x8 wV0 = *(const bf16x8*)&Wt[(size_t)(jV + lr) * 64 + lg * 8];
    const bf16x8 wV1 = *(const bf16x8*)&Wt[(size_t)(jV + lr) * 64 + 32 + lg * 8];
    const float bK = b_qkv[jK + lr];
    const float bQ = b_qkv[jQ + lr];
    const float bV = b_qkv[jV + lr];

    int R = e - s;
    if (R <= 0) return;
    if (R > RMAX) R = RMAX;             // safety clamp (P ~ 1e-14)
    const int NT = (R + 15) >> 4;       // 16-row tiles (1..4)
    const int RT = NT * 16;
    const int KB = (RT + 31) >> 5;      // 32-key blocks (1..2)

    // zero V^T tail key-cols [RT, KB*32): uninitialized LDS there can hold
    // NaN bit-patterns and PV's 0*NaN would poison the accumulator (R7 bug).
    if (RT < KB * 32) {
        for (int idx = t; idx < 64 * 16; idx += 256) {
            const int dd = idx >> 4, cc = RT + (idx & 15);
            if (cc < KB * 32) Vs[dd][cc] = 0;
        }
    }

    // ---- QKV: one pass over row-tiles; K,Q,V together ----
    #pragma unroll
    for (int rt = 0; rt < 4; ++rt) {
        if (rt < NT) {
            int row = s + rt * 16 + lr;
            row = row < N ? row : N - 1;              // clamp (finite data)
            const bf16x8 a0 = *(const bf16x8*)&h1g[(size_t)row * 64 + lg * 8];
            const bf16x8 a1 = *(const bf16x8*)&h1g[(size_t)row * 64 + 32 + lg * 8];
            f32x4 dK = {0,0,0,0}, dQ = {0,0,0,0}, dV = {0,0,0,0};
            dK = __builtin_amdgcn_mfma_f32_16x16x32_bf16(a0, wK0, dK, 0, 0, 0);
            dK = __builtin_amdgcn_mfma_f32_16x16x32_bf16(a1, wK1, dK, 0, 0, 0);
            dQ = __builtin_amdgcn_mfma_f32_16x16x32_bf16(a0, wQ0, dQ, 0, 0, 0);
            dQ = __builtin_amdgcn_mfma_f32_16x16x32_bf16(a1, wQ1, dQ, 0, 0, 0);
            dV = __builtin_amdgcn_mfma_f32_16x16x32_bf16(a0, wV0, dV, 0, 0, 0);
            dV = __builtin_amdgcn_mfma_f32_16x16x32_bf16(a1, wV1, dV, 0, 0, 0);
            const int n4 = rt * 16 + lg * 4;
            #pragma unroll
            for (int r = 0; r < 4; ++r) {
                Ks[n4 + r][ct * 16 + lr] = f2bf(dK[r] + bK);
                Qs[n4 + r][ct * 16 + lr] = f2bf(dQ[r] + bQ);
            }
            union { unsigned short us[4]; uint2 u2; } pk;
            #pragma unroll
            for (int r = 0; r < 4; ++r) pk.us[r] = f2bf(dV[r] + bV);
            *(uint2*)&Vs[ct * 16 + lr][n4] = pk.u2;   // packed 8B, key-contig
        }
    }
    __syncthreads();

    bf16x8 ones;
    #pragma unroll
    for (int j = 0; j < 8; ++j) ones[j] = (short)0x3F80;   // bf16 1.0

    const int KT2 = 2 * KB;             // key tiles incl. padding (2 or 4)
    const int ksh = KB;                 // log2(KT2): KB=1->1, KB=2->2

    // ---- phase 1: QK^T score tiles, wave per (qt, kt) 16x16 tile ----
    for (int c = wv; c < NT * KT2; c += 4) {
        const int qt = c >> ksh, kt = c & (KT2 - 1);
        if (kt < NT) {
            const bf16x8 qf0 = *(const bf16x8*)&Qs[qt * 16 + lr][lg * 8];
            const bf16x8 qf1 = *(const bf16x8*)&Qs[qt * 16 + lr][32 + lg * 8];
            const bf16x8 kf0 = *(const bf16x8*)&Ks[kt * 16 + lr][lg * 8];
            const bf16x8 kf1 = *(const bf16x8*)&Ks[kt * 16 + lr][32 + lg * 8];
            f32x4 dsc = {0.f, 0.f, 0.f, 0.f};
            dsc = __builtin_amdgcn_mfma_f32_16x16x32_bf16(qf0, kf0, dsc, 0, 0, 0);
            dsc = __builtin_amdgcn_mfma_f32_16x16x32_bf16(qf1, kf1, dsc, 0, 0, 0);
            const bool valid = (kt * 16 + lr) < R;   // uniform in-segment mask
            #pragma unroll
            for (int r = 0; r < 4; ++r)
                Ps[qt * 16 + lg * 4 + r][kt * 16 + lr] =
                    valid ? f2bf(__expf(dsc[r] * SCALE)) : 0;
        } else {
            #pragma unroll
            for (int r = 0; r < 4; ++r)
                Ps[qt * 16 + lg * 4 + r][kt * 16 + lr] = 0;
        }
    }
    __syncthreads();   // Ps tiles cross waves now

    // ---- phase 2: PV, wave per (qt, 32-d-col half); O -> dead Qs ----
    for (int c = wv; c < NT * 2; c += 4) {
        const int qt = c >> 1, half = c & 1;
        f32x4 oA = {0,0,0,0}, oB = {0,0,0,0}, sac = {0,0,0,0};
        for (int kb = 0; kb < KB; ++kb) {
            const bf16x8 pa = *(const bf16x8*)&Ps[qt * 16 + lr][kb * 32 + lg * 8];
            sac = __builtin_amdgcn_mfma_f32_16x16x32_bf16(pa, ones, sac, 0, 0, 0);
            const bf16x8 vA = *(const bf16x8*)&Vs[half * 32 + lr][kb * 32 + lg * 8];
            const bf16x8 vB = *(const bf16x8*)&Vs[half * 32 + 16 + lr][kb * 32 + lg * 8];
            oA = __builtin_amdgcn_mfma_f32_16x16x32_bf16(pa, vA, oA, 0, 0, 0);
            oB = __builtin_amdgcn_mfma_f32_16x16x32_bf16(pa, vB, oB, 0, 0, 0);
        }
        #pragma unroll
        for (int r = 0; r < 4; ++r) {
            const float inv = 1.f / sac[r];
            const int q = qt * 16 + lg * 4 + r;
            Qs[q][half * 32 + lr]      = f2bf(oA[r] * inv);
            Qs[q][half * 32 + 16 + lr] = f2bf(oB[r] * inv);
        }
        asm volatile("s_waitcnt lgkmcnt(0)" ::: "memory");  // same-wave LDS RAW
        const int qi = lane >> 2;                  // 16 rows x 4 lanes
        const int q  = qt * 16 + qi;
        const int dd = half * 32 + (lane & 3) * 8;
        if (q < R)
            *(bf16x8*)(attb + (size_t)(s + q) * D + h * 64 + dd) =
                *(const bf16x8*)&Qs[q][dd];
    }
}

// ---------------------------------------------------------------------------
// Kernel C: LN2 over D=512 + out projection. 32 rows/block -> 192 blocks
// (0.75 dispatch rounds on 256 CUs; R15's 384 blocks = 1.5 rounds with a
// half-idle second round). Vectorized bf16x8 loads; dual 8-deep MFMA chains.
// ---------------------------------------------------------------------------
__global__ __launch_bounds__(256) void ln2_out_kernel(
    const unsigned short* __restrict__ att, const float* __restrict__ g,
    const float* __restrict__ b, const unsigned short* __restrict__ Wot,
    const float* __restrict__ bias, float* __restrict__ y)
{
    __shared__ unsigned short h2[32][520];   // 33.3 KB -> 4 blocks/CU
    const int t = threadIdx.x, lane = t & 63, wv = t >> 6;
    const int row0 = blockIdx.x * 32;
    const int lr = lane & 15, lg = lane >> 4;

    const float4 ga = *(const float4*)&g[lane * 8];
    const float4 gb = *(const float4*)&g[lane * 8 + 4];
    const float4 ba = *(const float4*)&b[lane * 8];
    const float4 bb = *(const float4*)&b[lane * 8 + 4];
    const float gv[8] = {ga.x, ga.y, ga.z, ga.w, gb.x, gb.y, gb.z, gb.w};
    const float bv[8] = {ba.x, ba.y, ba.z, ba.w, bb.x, bb.y, bb.z, bb.w};

    #pragma unroll
    for (int i = 0; i < 8; ++i) {
        const int r = wv * 8 + i;
        const bf16x8 v8 = *(const bf16x8*)(att + (size_t)(row0 + r) * D + lane * 8);
        float vals[8];
        float sm = 0.f, sq = 0.f;
        #pragma unroll
        for (int c = 0; c < 8; ++c) {
            vals[c] = bf2f((unsigned short)v8[c]);
            sm += vals[c];
            sq += vals[c] * vals[c];
        }
        #pragma unroll
        for (int off = 1; off < 64; off <<= 1) {
            sm += __shfl_xor(sm, off);
            sq += __shfl_xor(sq, off);
        }
        const float mean = sm * (1.f / 512.f);
        const float var  = sq * (1.f / 512.f) - mean * mean;
        const float rstd = rsqrtf(var + EPS);
        bf16x8 hv;
        #pragma unroll
        for (int c = 0; c < 8; ++c)
            hv[c] = (short)f2bf((vals[c] - mean) * rstd * gv[c] + bv[c]);
        *(bf16x8*)&h2[r][lane * 8] = hv;              // one 16B LDS store
    }
    __syncthreads();

    const int j0 = wv * 16;
    const float bj = bias[j0 + lr];
    #pragma unroll
    for (int tile = 0; tile < 2; ++tile) {
        f32x4 acc0 = {0.f, 0.f, 0.f, 0.f};
        f32x4 acc1 = {0.f, 0.f, 0.f, 0.f};
        #pragma unroll
        for (int ks = 0; ks < 8; ++ks) {
            const bf16x8 a0 = *(const bf16x8*)&h2[tile * 16 + lr][ks * 32 + lg * 8];
            const bf16x8 w0 = *(const bf16x8*)&Wot[(size_t)(j0 + lr) * D + ks * 32 + lg * 8];
            acc0 = __builtin_amdgcn_mfma_f32_16x16x32_bf16(a0, w0, acc0, 0, 0, 0);
            const bf16x8 a1 = *(const bf16x8*)&h2[tile * 16 + lr][(ks + 8) * 32 + lg * 8];
            const bf16x8 w1 = *(const bf16x8*)&Wot[(size_t)(j0 + lr) * D + (ks + 8) * 32 + lg * 8];
            acc1 = __builtin_amdgcn_mfma_f32_16x16x32_bf16(a1, w1, acc1, 0, 0, 0);
        }
        const f32x4 acc = acc0 + acc1;
        #pragma unroll
        for (int r = 0; r < 4; ++r)
            y[(size_t)(row0 + tile * 16 + lg * 4 + r) * 64 + j0 + lr] = acc[r] + bj;
    }
}

// ---------------------------------------------------------------------------
extern "C" void kernel_launch(void* const* d_in, const int* in_sizes, int n_in,
                              void* d_out, int out_size, void* d_ws, size_t ws_size,
                              hipStream_t stream) {
    const float* x     = (const float*)d_in[0];
    const int*   batch = (const int*)  d_in[1];
    const float* ln1_g = (const float*)d_in[2];
    const float* ln1_b = (const float*)d_in[3];
    const float* W_qkv = (const float*)d_in[4];
    const float* b_qkv = (const float*)d_in[5];
    const float* ln2_g = (const float*)d_in[6];
    const float* ln2_b = (const float*)d_in[7];
    const float* W_out = (const float*)d_in[8];
    const float* b_out = (const float*)d_in[9];
    float* y = (float*)d_out;

    unsigned short* Wt   = (unsigned short*)d_ws;         // [1536][64] bf16
    unsigned short* Wot  = Wt  + (size_t)TD * 64;         // [64][512] bf16
    unsigned short* h1g  = Wot + (size_t)64 * D;          // [N][64] bf16
    unsigned short* attb = h1g + (size_t)N * 64;          // [N][512] bf16
    int* bound = (int*)(attb + (size_t)N * D);            // [257]

    hipLaunchKernelGGL(prep_kernel, dim3(856), dim3(256), 0, stream,
                       x, ln1_g, ln1_b, W_qkv, W_out, batch, Wt, Wot, bound, h1g);
    hipLaunchKernelGGL(seghead_kernel, dim3(256, 8), dim3(256), 0, stream,
                       h1g, Wt, b_qkv, bound, attb);
    hipLaunchKernelGGL(ln2_out_kernel, dim3(N / 32), dim3(256), 0, stream,
                       attb, ln2_g, ln2_b, Wot, b_out, y);
}

// Round 17
// 32.650 us; speedup vs baseline: 1.0081x; 1.0081x over previous
//
#include <hip/hip_runtime.h>
#include <math.h>

#define N 6144
#define E 64
#define H 8
#define D 512
#define TD 1536  // 3*D
#define EPS 1e-5f
#define SCALE 0.04419417382415922f  // 1/sqrt(512)
#define RMAX 64   // max segment size; multinomial max ~41, P(>64) ~1e-14

typedef __attribute__((ext_vector_type(8))) short bf16x8;
typedef __attribute__((ext_vector_type(4))) float f32x4;

static __device__ __forceinline__ unsigned short f2bf(float f) {
    union { float f; unsigned int u; } v; v.f = f;
    unsigned int r = v.u + 0x7FFFu + ((v.u >> 16) & 1u);  // RNE
    return (unsigned short)(r >> 16);
}
static __device__ __forceinline__ float bf2f(unsigned short u) {
    union { unsigned int u; float f; } v; v.u = ((unsigned int)u) << 16;
    return v.f;
}

// ---------------------------------------------------------------------------
// Kernel 0: prep. Blocks [0,24): bound table. [24,72): Wt transpose — one
// thread per (j, k-octet): 8 coalesced f32 loads + ONE 16B store. [72,88):
// Wot same scheme. [88,1624): LN1 -> h1 bf16 [N][64], one row per wave
// (R10 lesson: keep LN1 at full parallelism; R16 lesson: halving block
// count here is neutral — blocks pipeline across dispatch rounds).
// ---------------------------------------------------------------------------
__global__ __launch_bounds__(256) void prep_kernel(
    const float* __restrict__ x, const float* __restrict__ ln1g,
    const float* __restrict__ ln1b, const float* __restrict__ W_qkv,
    const float* __restrict__ W_out, const int* __restrict__ batch,
    unsigned short* __restrict__ Wt, unsigned short* __restrict__ Wot,
    int* __restrict__ bound, unsigned short* __restrict__ h1g)
{
    const int t = threadIdx.x, lane = t & 63, wv = t >> 6;
    const int bx = blockIdx.x;
    if (bx < 24) {                                     // bound table
        const int tid = bx * 256 + t;
        const int bv = batch[tid];
        const int prev = tid ? batch[tid - 1] : -1;
        if (bv != prev)
            for (int v = prev + 1; v <= bv; ++v) bound[v] = tid;
        if (tid == N - 1)
            for (int v = bv + 1; v <= 256; ++v) bound[v] = N;
    } else if (bx < 72) {                              // Wt[j][k] = W_qkv[k][j]
        const int w = (bx - 24) * 256 + t;             // [0, 12288)
        const int j = w % TD, ko = w / TD;             // ko in [0,8)
        bf16x8 o;
        #pragma unroll
        for (int i = 0; i < 8; ++i)                    // coalesced across j
            o[i] = (short)f2bf(W_qkv[(size_t)(ko * 8 + i) * TD + j]);
        *(bf16x8*)&Wt[(size_t)j * 64 + ko * 8] = o;    // one 16B store
    } else if (bx < 88) {                              // Wot[j][k] = W_out[k][j]
        const int w = (bx - 72) * 256 + t;             // [0, 4096)
        const int j = w & 63, ko = w >> 6;             // ko in [0,64)
        bf16x8 o;
        #pragma unroll
        for (int i = 0; i < 8; ++i)                    // coalesced across j
            o[i] = (short)f2bf(W_out[(size_t)(ko * 8 + i) * 64 + j]);
        *(bf16x8*)&Wot[(size_t)j * 512 + ko * 8] = o;  // one 16B store
    } else {                                           // LN1 rows
        const int row = (bx - 88) * 4 + wv;            // [0, 6144)
        const float v = x[(size_t)row * E + lane];
        float sm = v, sq = v * v;
        #pragma unroll
        for (int off = 1; off < 64; off <<= 1) {
            sm += __shfl_xor(sm, off);
            sq += __shfl_xor(sq, off);
        }
        const float mean = sm * (1.f / 64.f);
        const float var  = sq * (1.f / 64.f) - mean * mean;
        h1g[(size_t)row * 64 + lane] =
            f2bf((v - mean) * rsqrtf(var + EPS) * ln1g[lane] + ln1b[lane]);
    }
}

// ---------------------------------------------------------------------------
// Kernel 1: one block per (segment, head). QKV (wave per column-tile), then
// attention with two-level wave split (R14):
//   phase 1: wave per (qt, kt) 16x16 score tile -> Ps; __syncthreads;
//   phase 2: wave per (qt, 32-col half) PV; O bounced through dead Qs
//            (NOT Ps — other waves still read Ps) -> coalesced 16B stores.
// Fusion ruled out by measurement: grid-sync (R5), agent atomics (R12).
// Frag maps (verified R3-R16): A[row=lr][k=lg*8+j], B[col=lr][k=lg*8+j],
// D[col=lr][row=lg*4+r].
// ---------------------------------------------------------------------------
__global__ __launch_bounds__(256) void seghead_kernel(
    const unsigned short* __restrict__ h1g, const unsigned short* __restrict__ Wt,
    const float* __restrict__ b_qkv, const int* __restrict__ bound,
    unsigned short* __restrict__ attb)
{
    __shared__ unsigned short Qs[RMAX][72];     // per-head Q [q][d] / O bounce
    __shared__ unsigned short Ks[RMAX][72];     // per-head K [key][d]
    __shared__ unsigned short Vs[64][72];       // per-head V^T [d][key]
    __shared__ unsigned short Ps[RMAX][72];     // P [q][key]

    const int t = threadIdx.x, lane = t & 63, wv = t >> 6;
    const int lr = lane & 15, lg = lane >> 4;
    const int b = blockIdx.x, h = blockIdx.y;

    // bound loads first: longest scalar dependency chain (R -> NT/KB/loops)
    const int s = bound[b];
    const int e = bound[b + 1];

    // W fragments for this wave's column tile (overlap under bound latency)
    const int ct = wv;
    const int jK = h * 64 + ct * 16;
    const int jQ = 512 + jK;
    const int jV = 1024 + jK;
    const bf16x8 wK0 = *(const bf16x8*)&Wt[(size_t)(jK + lr) * 64 + lg * 8];
    const bf16x8 wK1 = *(const bf16x8*)&Wt[(size_t)(jK + lr) * 64 + 32 + lg * 8];
    const bf16x8 wQ0 = *(const bf16x8*)&Wt[(size_t)(jQ + lr) * 64 + lg * 8];
    const bf16x8 wQ1 = *(const bf16x8*)&Wt[(size_t)(jQ + lr) * 64 + 32 + lg * 8];
    const bf16x8 wV0 = *(const bf16x8*)&Wt[(size_t)(jV + lr) * 64 + lg * 8];
    const bf16x8 wV1 = *(const bf16x8*)&Wt[(size_t)(jV + lr) * 64 + 32 + lg * 8];
    const float bK = b_qkv[jK + lr];
    const float bQ = b_qkv[jQ + lr];
    const float bV = b_qkv[jV + lr];

    int R = e - s;
    if (R <= 0) return;
    if (R > RMAX) R = RMAX;             // safety clamp (P ~ 1e-14)
    const int NT = (R + 15) >> 4;       // 16-row tiles (1..4)
    const int RT = NT * 16;
    const int KB = (RT + 31) >> 5;      // 32-key blocks (1..2)

    // zero V^T tail key-cols [RT, KB*32): uninitialized LDS there can hold
    // NaN bit-patterns and PV's 0*NaN would poison the accumulator (R7 bug).
    if (RT < KB * 32) {
        for (int idx = t; idx < 64 * 16; idx += 256) {
            const int dd = idx >> 4, cc = RT + (idx & 15);
            if (cc < KB * 32) Vs[dd][cc] = 0;
        }
    }

    // ---- QKV: one pass over row-tiles; K,Q,V together ----
    #pragma unroll
    for (int rt = 0; rt < 4; ++rt) {
        if (rt < NT) {
            int row = s + rt * 16 + lr;
            row = row < N ? row : N - 1;              // clamp (finite data)
            const bf16x8 a0 = *(const bf16x8*)&h1g[(size_t)row * 64 + lg * 8];
            const bf16x8 a1 = *(const bf16x8*)&h1g[(size_t)row * 64 + 32 + lg * 8];
            f32x4 dK = {0,0,0,0}, dQ = {0,0,0,0}, dV = {0,0,0,0};
            dK = __builtin_amdgcn_mfma_f32_16x16x32_bf16(a0, wK0, dK, 0, 0, 0);
            dK = __builtin_amdgcn_mfma_f32_16x16x32_bf16(a1, wK1, dK, 0, 0, 0);
            dQ = __builtin_amdgcn_mfma_f32_16x16x32_bf16(a0, wQ0, dQ, 0, 0, 0);
            dQ = __builtin_amdgcn_mfma_f32_16x16x32_bf16(a1, wQ1, dQ, 0, 0, 0);
            dV = __builtin_amdgcn_mfma_f32_16x16x32_bf16(a0, wV0, dV, 0, 0, 0);
            dV = __builtin_amdgcn_mfma_f32_16x16x32_bf16(a1, wV1, dV, 0, 0, 0);
            const int n4 = rt * 16 + lg * 4;
            #pragma unroll
            for (int r = 0; r < 4; ++r) {
                Ks[n4 + r][ct * 16 + lr] = f2bf(dK[r] + bK);
                Qs[n4 + r][ct * 16 + lr] = f2bf(dQ[r] + bQ);
            }
            union { unsigned short us[4]; uint2 u2; } pk;
            #pragma unroll
            for (int r = 0; r < 4; ++r) pk.us[r] = f2bf(dV[r] + bV);
            *(uint2*)&Vs[ct * 16 + lr][n4] = pk.u2;   // packed 8B, key-contig
        }
    }
    __syncthreads();

    bf16x8 ones;
    #pragma unroll
    for (int j = 0; j < 8; ++j) ones[j] = (short)0x3F80;   // bf16 1.0

    const int KT2 = 2 * KB;             // key tiles incl. padding (2 or 4)
    const int ksh = KB;                 // log2(KT2): KB=1->1, KB=2->2

    // ---- phase 1: QK^T score tiles, wave per (qt, kt) 16x16 tile ----
    for (int c = wv; c < NT * KT2; c += 4) {
        const int qt = c >> ksh, kt = c & (KT2 - 1);
        if (kt < NT) {
            const bf16x8 qf0 = *(const bf16x8*)&Qs[qt * 16 + lr][lg * 8];
            const bf16x8 qf1 = *(const bf16x8*)&Qs[qt * 16 + lr][32 + lg * 8];
            const bf16x8 kf0 = *(const bf16x8*)&Ks[kt * 16 + lr][lg * 8];
            const bf16x8 kf1 = *(const bf16x8*)&Ks[kt * 16 + lr][32 + lg * 8];
            f32x4 dsc = {0.f, 0.f, 0.f, 0.f};
            dsc = __builtin_amdgcn_mfma_f32_16x16x32_bf16(qf0, kf0, dsc, 0, 0, 0);
            dsc = __builtin_amdgcn_mfma_f32_16x16x32_bf16(qf1, kf1, dsc, 0, 0, 0);
            const bool valid = (kt * 16 + lr) < R;   // uniform in-segment mask
            #pragma unroll
            for (int r = 0; r < 4; ++r)
                Ps[qt * 16 + lg * 4 + r][kt * 16 + lr] =
                    valid ? f2bf(__expf(dsc[r] * SCALE)) : 0;
        } else {
            #pragma unroll
            for (int r = 0; r < 4; ++r)
                Ps[qt * 16 + lg * 4 + r][kt * 16 + lr] = 0;
        }
    }
    __syncthreads();   // Ps tiles cross waves now

    // ---- phase 2: PV, wave per (qt, 32-d-col half); O -> dead Qs ----
    for (int c = wv; c < NT * 2; c += 4) {
        const int qt = c >> 1, half = c & 1;
        f32x4 oA = {0,0,0,0}, oB = {0,0,0,0}, sac = {0,0,0,0};
        for (int kb = 0; kb < KB; ++kb) {
            const bf16x8 pa = *(const bf16x8*)&Ps[qt * 16 + lr][kb * 32 + lg * 8];
            sac = __builtin_amdgcn_mfma_f32_16x16x32_bf16(pa, ones, sac, 0, 0, 0);
            const bf16x8 vA = *(const bf16x8*)&Vs[half * 32 + lr][kb * 32 + lg * 8];
            const bf16x8 vB = *(const bf16x8*)&Vs[half * 32 + 16 + lr][kb * 32 + lg * 8];
            oA = __builtin_amdgcn_mfma_f32_16x16x32_bf16(pa, vA, oA, 0, 0, 0);
            oB = __builtin_amdgcn_mfma_f32_16x16x32_bf16(pa, vB, oB, 0, 0, 0);
        }
        #pragma unroll
        for (int r = 0; r < 4; ++r) {
            const float inv = 1.f / sac[r];
            const int q = qt * 16 + lg * 4 + r;
            Qs[q][half * 32 + lr]      = f2bf(oA[r] * inv);
            Qs[q][half * 32 + 16 + lr] = f2bf(oB[r] * inv);
        }
        asm volatile("s_waitcnt lgkmcnt(0)" ::: "memory");  // same-wave LDS RAW
        const int qi = lane >> 2;                  // 16 rows x 4 lanes
        const int q  = qt * 16 + qi;
        const int dd = half * 32 + (lane & 3) * 8;
        if (q < R)
            *(bf16x8*)(attb + (size_t)(s + q) * D + h * 64 + dd) =
                *(const bf16x8*)&Qs[q][dd];
    }
}

// ---------------------------------------------------------------------------
// Kernel C: LN2 over D=512 + out projection. Vectorized bf16x8 input loads;
// K=512 accumulation split into two independent 8-deep MFMA chains (ILP).
// 384 blocks of 16 rows (R16 lesson: 192x32-row is neutral — rounds pipeline).
// ---------------------------------------------------------------------------
__global__ __launch_bounds__(256) void ln2_out_kernel(
    const unsigned short* __restrict__ att, const float* __restrict__ g,
    const float* __restrict__ b, const unsigned short* __restrict__ Wot,
    const float* __restrict__ bias, float* __restrict__ y)
{
    __shared__ unsigned short h2[16][520];
    const int t = threadIdx.x, lane = t & 63, wv = t >> 6;
    const int row0 = blockIdx.x * 16;
    const int lr = lane & 15, lg = lane >> 4;

    const float4 ga = *(const float4*)&g[lane * 8];
    const float4 gb = *(const float4*)&g[lane * 8 + 4];
    const float4 ba = *(const float4*)&b[lane * 8];
    const float4 bb = *(const float4*)&b[lane * 8 + 4];
    const float gv[8] = {ga.x, ga.y, ga.z, ga.w, gb.x, gb.y, gb.z, gb.w};
    const float bv[8] = {ba.x, ba.y, ba.z, ba.w, bb.x, bb.y, bb.z, bb.w};

    #pragma unroll
    for (int i = 0; i < 4; ++i) {
        const int r = wv * 4 + i;
        const bf16x8 v8 = *(const bf16x8*)(att + (size_t)(row0 + r) * D + lane * 8);
        float vals[8];
        float sm = 0.f, sq = 0.f;
        #pragma unroll
        for (int c = 0; c < 8; ++c) {
            vals[c] = bf2f((unsigned short)v8[c]);
            sm += vals[c];
            sq += vals[c] * vals[c];
        }
        #pragma unroll
        for (int off = 1; off < 64; off <<= 1) {
            sm += __shfl_xor(sm, off);
            sq += __shfl_xor(sq, off);
        }
        const float mean = sm * (1.f / 512.f);
        const float var  = sq * (1.f / 512.f) - mean * mean;
        const float rstd = rsqrtf(var + EPS);
        bf16x8 hv;
        #pragma unroll
        for (int c = 0; c < 8; ++c)
            hv[c] = (short)f2bf((vals[c] - mean) * rstd * gv[c] + bv[c]);
        *(bf16x8*)&h2[r][lane * 8] = hv;              // one 16B LDS store
    }
    __syncthreads();

    const int j0 = wv * 16;
    f32x4 acc0 = {0.f, 0.f, 0.f, 0.f};
    f32x4 acc1 = {0.f, 0.f, 0.f, 0.f};
    #pragma unroll
    for (int ks = 0; ks < 8; ++ks) {
        const bf16x8 a0 = *(const bf16x8*)&h2[lr][ks * 32 + lg * 8];
        const bf16x8 w0 = *(const bf16x8*)&Wot[(size_t)(j0 + lr) * D + ks * 32 + lg * 8];
        acc0 = __builtin_amdgcn_mfma_f32_16x16x32_bf16(a0, w0, acc0, 0, 0, 0);
        const bf16x8 a1 = *(const bf16x8*)&h2[lr][(ks + 8) * 32 + lg * 8];
        const bf16x8 w1 = *(const bf16x8*)&Wot[(size_t)(j0 + lr) * D + (ks + 8) * 32 + lg * 8];
        acc1 = __builtin_amdgcn_mfma_f32_16x16x32_bf16(a1, w1, acc1, 0, 0, 0);
    }
    const f32x4 acc = acc0 + acc1;
    const float bj = bias[j0 + lr];
    #pragma unroll
    for (int r = 0; r < 4; ++r)
        y[(size_t)(row0 + lg * 4 + r) * 64 + j0 + lr] = acc[r] + bj;
}

// ---------------------------------------------------------------------------
extern "C" void kernel_launch(void* const* d_in, const int* in_sizes, int n_in,
                              void* d_out, int out_size, void* d_ws, size_t ws_size,
                              hipStream_t stream) {
    const float* x     = (const float*)d_in[0];
    const int*   batch = (const int*)  d_in[1];
    const float* ln1_g = (const float*)d_in[2];
    const float* ln1_b = (const float*)d_in[3];
    const float* W_qkv = (const float*)d_in[4];
    const float* b_qkv = (const float*)d_in[5];
    const float* ln2_g = (const float*)d_in[6];
    const float* ln2_b = (const float*)d_in[7];
    const float* W_out = (const float*)d_in[8];
    const float* b_out = (const float*)d_in[9];
    float* y = (float*)d_out;

    unsigned short* Wt   = (unsigned short*)d_ws;         // [1536][64] bf16
    unsigned short* Wot  = Wt  + (size_t)TD * 64;         // [64][512] bf16
    unsigned short* h1g  = Wot + (size_t)64 * D;          // [N][64] bf16
    unsigned short* attb = h1g + (size_t)N * 64;          // [N][512] bf16
    int* bound = (int*)(attb + (size_t)N * D);            // [257]

    hipLaunchKernelGGL(prep_kernel, dim3(1624), dim3(256), 0, stream,
                       x, ln1_g, ln1_b, W_qkv, W_out, batch, Wt, Wot, bound, h1g);
    hipLaunchKernelGGL(seghead_kernel, dim3(256, 8), dim3(256), 0, stream,
                       h1g, Wt, b_qkv, bound, attb);
    hipLaunchKernelGGL(ln2_out_kernel, dim3(N / 16), dim3(256), 0, stream,
                       attb, ln2_g, ln2_b, Wot, b_out, y);
}